// Round 11
// baseline (206.022 us; speedup 1.0000x reference)
//
#include <hip/hip_runtime.h>
#include <hip/hip_bf16.h>

#define IN_CH 64
#define HC 128          // HEADS * OUT_CH
#define HEADS 8
#define OUT_CH 16
#define NEG 0.2f
#define PROJ_NPI 32     // nodes per block in proj kernel

#define BK_BITS 10
#define BK_SIZE 1024    // nodes per bucket
#define BK_CAP 18432    // padded capacity per bucket (mean 16384, 16-sigma margin)
#define BIN_CHUNK 4096  // edges per b3 block

__device__ __forceinline__ float lrelu(float x) {
    return fmaxf(x, NEG * x);   // valid for NEG<1
}

// ---- projection v4: W column in registers, x via LDS broadcast ----
// Round-8 structure was LDS-pipe-bound (64-lane-distinct W b128 reads, 3:1
// LDS:VALU per CU). Here thread owns col c with wreg[64]=W[:,c] in VGPRs;
// x reads are same-address LDS broadcasts (near-free). k-loop fully unrolled
// so wreg indexing is compile-time (no scratch).
__global__ __launch_bounds__(256, 4) void proj_kernel(
    const float* __restrict__ x, const float* __restrict__ W,
    const float* __restrict__ att_src, const float* __restrict__ att_dst,
    __hip_bfloat16* __restrict__ hb, float* __restrict__ asrc,
    float* __restrict__ adst, int n)
{
    __shared__ float sx[PROJ_NPI * IN_CH];   // 8 KB
    int tid  = threadIdx.x;
    int c    = tid & 127;      // output column (spans 2 waves per npar group)
    int npar = tid >> 7;       // node parity

    // W[:,c] resident in registers (64 VGPR); coalesced dword loads
    float wreg[IN_CH];
    #pragma unroll
    for (int k = 0; k < IN_CH; ++k) wreg[k] = W[k * HC + c];

    float asw = att_src[c];
    float adw = att_dst[c];
    int head = c >> 4;
    int cl   = c & 15;         // == lane&15 within the 16-lane head group

    int node0 = blockIdx.x * PROJ_NPI;
    {
        const float4* x4 = (const float4*)(x + (long long)node0 * IN_CH);
        float4* sx4w = (float4*)sx;
        int nvalid4 = min(PROJ_NPI, n - node0) * (IN_CH / 4);
        #pragma unroll
        for (int i = 0; i < 2; ++i) {
            int idx = tid + i * 256;
            if (idx < nvalid4) sx4w[idx] = x4[idx];
        }
    }
    __syncthreads();

    const float4* sx4 = (const float4*)sx;
    for (int i = 0; i < PROJ_NPI / 2; ++i) {
        int nl = i * 2 + npar;
        int node = node0 + nl;
        if (node >= n) break;

        float acc = 0.f;
        #pragma unroll
        for (int kq = 0; kq < 16; ++kq) {       // full unroll: wreg idx static
            float4 xv = sx4[nl * 16 + kq];      // same-addr broadcast read
            acc = fmaf(xv.x, wreg[kq * 4 + 0], acc);
            acc = fmaf(xv.y, wreg[kq * 4 + 1], acc);
            acc = fmaf(xv.z, wreg[kq * 4 + 2], acc);
            acc = fmaf(xv.w, wreg[kq * 4 + 3], acc);
        }

        hb[(long long)node * HC + c] = __float2bfloat16(acc);

        float vs = acc * asw;
        float vd = acc * adw;
        #pragma unroll
        for (int m = 8; m >= 1; m >>= 1) {
            vs += __shfl_xor(vs, m, 64);
            vd += __shfl_xor(vd, m, 64);
        }
        if (cl == 0) {
            asrc[node * HEADS + head] = vs;
            adst[node * HEADS + head] = vd;
        }
    }
}

// ---- bucketed CSR build (fixed-capacity padded buckets) ----
__global__ void cinit_kernel(int* __restrict__ cursor, int nbuck)
{
    int t = threadIdx.x;
    if (t < nbuck) cursor[t] = t * BK_CAP;
}

__global__ __launch_bounds__(256) void b3_bin(
    const int* __restrict__ ei, int E, int nbuck,
    int* __restrict__ cursor, unsigned* __restrict__ binned)
{
    __shared__ int cnt[256];
    __shared__ int resv[256];
    int tid = threadIdx.x;
    int chunk0 = blockIdx.x * BIN_CHUNK;
    cnt[tid] = 0;
    __syncthreads();
    for (int i = tid; i < BIN_CHUNK; i += 256) {
        int e = chunk0 + i;
        if (e < E) atomicAdd(&cnt[ei[E + e] >> BK_BITS], 1);
    }
    __syncthreads();
    if (tid < nbuck) resv[tid] = cnt[tid] ? atomicAdd(&cursor[tid], cnt[tid]) : 0;
    __syncthreads();
    for (int i = tid; i < BIN_CHUNK; i += 256) {
        int e = chunk0 + i;
        if (e < E) {
            int s = ei[e], d = ei[E + e];
            int b = d >> BK_BITS;
            int p = atomicAdd(&resv[b], 1);
            binned[p] = (unsigned)s | ((unsigned)(d & (BK_SIZE - 1)) << 20);
        }
    }
}

__global__ __launch_bounds__(256) void b4_build(
    const unsigned* __restrict__ binned, const int* __restrict__ cursor,
    int2* __restrict__ row2, int* __restrict__ csr, int n)
{
    __shared__ int deg[BK_SIZE];
    __shared__ int off[BK_SIZE];
    __shared__ int ts[256];
    int tid = threadIdx.x;
    int b = blockIdx.x;
    int node0 = b << BK_BITS;
    int nn = min(BK_SIZE, n - node0);
    int e0 = b * BK_CAP;
    int e1 = cursor[b];     // final cursor = e0 + bucket count

    for (int i = tid; i < BK_SIZE; i += 256) deg[i] = 0;
    __syncthreads();
    for (int j = e0 + tid; j < e1; j += 256)
        atomicAdd(&deg[binned[j] >> 20], 1);
    __syncthreads();

    int base4 = tid * 4;
    int v0 = deg[base4], v1 = deg[base4 + 1], v2 = deg[base4 + 2], v3 = deg[base4 + 3];
    int ssum = v0 + v1 + v2 + v3;
    ts[tid] = ssum;
    __syncthreads();
    for (int o = 1; o < 256; o <<= 1) {
        int xv = (tid >= o) ? ts[tid - o] : 0;
        __syncthreads();
        ts[tid] += xv;
        __syncthreads();
    }
    int run = ts[tid] - ssum;
    off[base4 + 0] = run;
    if (base4 + 0 < nn) row2[node0 + base4 + 0] = make_int2(e0 + run, e0 + run + v0);
    run += v0;
    off[base4 + 1] = run;
    if (base4 + 1 < nn) row2[node0 + base4 + 1] = make_int2(e0 + run, e0 + run + v1);
    run += v1;
    off[base4 + 2] = run;
    if (base4 + 2 < nn) row2[node0 + base4 + 2] = make_int2(e0 + run, e0 + run + v2);
    run += v2;
    off[base4 + 3] = run;
    if (base4 + 3 < nn) row2[node0 + base4 + 3] = make_int2(e0 + run, e0 + run + v3);
    __syncthreads();

    for (int i = tid; i < BK_SIZE; i += 256) deg[i] = off[i];
    __syncthreads();
    for (int j = e0 + tid; j < e1; j += 256) {
        unsigned pk = binned[j];
        int dl = pk >> 20;
        int s = (int)(pk & 0xFFFFFu);
        int p = atomicAdd(&deg[dl], 1);
        csr[e0 + p] = s;
    }
}

// ---- fused softmax + aggregation: own-head exp, no cross-lane ops ----
__global__ __launch_bounds__(256) void agg_kernel(
    const int* __restrict__ csr, const int2* __restrict__ row2,
    const float* __restrict__ asrc, const float* __restrict__ adst,
    const __hip_bfloat16* __restrict__ hb, const float* __restrict__ bias,
    float* __restrict__ out, int n)
{
    int wave = threadIdx.x >> 6;
    int lane = threadIdx.x & 63;
    int d = blockIdx.x * 4 + wave;
    if (d >= n) return;

    int hO = lane >> 3;         // head owning this lane's output cols

    int2 se = row2[d];
    int start = se.x, end = se.y;

    float adstv = adst[d * HEADS + hO];
    const unsigned* hu = (const unsigned*)hb;

    // self loop
    float w = __expf(lrelu(asrc[d * HEADS + hO] + adstv));
    unsigned u = hu[(long long)d * 64 + lane];
    float denom = w;
    float accx = w * __uint_as_float(u << 16);
    float accy = w * __uint_as_float(u & 0xFFFF0000u);

    int j = start;
    for (; j + 3 < end; j += 4) {
        int s0 = csr[j], s1 = csr[j + 1], s2 = csr[j + 2], s3 = csr[j + 3];
        float w0 = __expf(lrelu(asrc[s0 * HEADS + hO] + adstv));
        float w1 = __expf(lrelu(asrc[s1 * HEADS + hO] + adstv));
        float w2 = __expf(lrelu(asrc[s2 * HEADS + hO] + adstv));
        float w3 = __expf(lrelu(asrc[s3 * HEADS + hO] + adstv));
        unsigned u0 = hu[(long long)s0 * 64 + lane];
        unsigned u1 = hu[(long long)s1 * 64 + lane];
        unsigned u2 = hu[(long long)s2 * 64 + lane];
        unsigned u3 = hu[(long long)s3 * 64 + lane];
        denom += (w0 + w1) + (w2 + w3);
        accx = fmaf(w0, __uint_as_float(u0 << 16), accx);
        accy = fmaf(w0, __uint_as_float(u0 & 0xFFFF0000u), accy);
        accx = fmaf(w1, __uint_as_float(u1 << 16), accx);
        accy = fmaf(w1, __uint_as_float(u1 & 0xFFFF0000u), accy);
        accx = fmaf(w2, __uint_as_float(u2 << 16), accx);
        accy = fmaf(w2, __uint_as_float(u2 & 0xFFFF0000u), accy);
        accx = fmaf(w3, __uint_as_float(u3 << 16), accx);
        accy = fmaf(w3, __uint_as_float(u3 & 0xFFFF0000u), accy);
    }
    for (; j < end; ++j) {
        int s0 = csr[j];
        float w0 = __expf(lrelu(asrc[s0 * HEADS + hO] + adstv));
        unsigned u0 = hu[(long long)s0 * 64 + lane];
        denom += w0;
        accx = fmaf(w0, __uint_as_float(u0 << 16), accx);
        accy = fmaf(w0, __uint_as_float(u0 & 0xFFFF0000u), accy);
    }

    float inv = 1.f / (denom + 1e-16f);
    const float2* b2 = (const float2*)bias;
    float2 bb = b2[lane];
    float2 o;
    o.x = fmaxf(fmaf(accx, inv, bb.x), 0.f);
    o.y = fmaxf(fmaf(accy, inv, bb.y), 0.f);
    ((float2*)out)[(long long)d * 64 + lane] = o;
}

extern "C" void kernel_launch(void* const* d_in, const int* in_sizes, int n_in,
                              void* d_out, int out_size, void* d_ws, size_t ws_size,
                              hipStream_t stream) {
    const float* x       = (const float*)d_in[0];
    const float* W       = (const float*)d_in[1];
    const float* att_src = (const float*)d_in[2];
    const float* att_dst = (const float*)d_in[3];
    const float* bias    = (const float*)d_in[4];
    const int*   ei      = (const int*)d_in[5];

    int n = in_sizes[0] / IN_CH;        // 100000
    int E = in_sizes[5] / 2;            // 1600000
    float* out = (float*)d_out;
    int nbuck = (n + BK_SIZE - 1) >> BK_BITS;   // 98 (<=256 required)

    // workspace layout
    char* ws = (char*)d_ws;
    __hip_bfloat16* hb = (__hip_bfloat16*)ws; ws += (size_t)n * HC * 2;  // 25.6 MB
    float* asrc = (float*)ws;   ws += (size_t)n * HEADS * 4;             // 3.2 MB
    float* adst = (float*)ws;   ws += (size_t)n * HEADS * 4;             // 3.2 MB
    int*   csr  = (int*)ws;     ws += ((size_t)nbuck * BK_CAP + 64) * 4; // 7.2 MB
    unsigned* binned = (unsigned*)ws; ws += (size_t)nbuck * BK_CAP * 4;  // 7.2 MB
    int2*  row2 = (int2*)ws;    ws += (size_t)n * 8;                     // 0.8 MB
    int*   cursor=(int*)ws;     ws += 256 * 4;

    int pblk = (n + PROJ_NPI - 1) / PROJ_NPI;   // 3125
    proj_kernel<<<pblk, 256, 0, stream>>>(x, W, att_src, att_dst,
                                          hb, asrc, adst, n);

    cinit_kernel<<<1, 256, 0, stream>>>(cursor, nbuck);
    int binblk = (E + BIN_CHUNK - 1) / BIN_CHUNK;
    b3_bin<<<binblk, 256, 0, stream>>>(ei, E, nbuck, cursor, binned);
    b4_build<<<nbuck, 256, 0, stream>>>(binned, cursor, row2, csr, n);

    int ablk = (n + 3) / 4;
    agg_kernel<<<ablk, 256, 0, stream>>>(csr, row2, asrc, adst, hb, bias, out, n);
}

// Round 12
// 178.251 us; speedup vs baseline: 1.1558x; 1.1558x over previous
//
#include <hip/hip_runtime.h>
#include <hip/hip_bf16.h>

#define IN_CH 64
#define HC 128          // HEADS * OUT_CH
#define HEADS 8
#define OUT_CH 16
#define NEG 0.2f

#define BK_BITS 10
#define BK_SIZE 1024    // nodes per bucket
#define BK_CAP 18432    // padded capacity per bucket (mean 16384, 16-sigma margin)
#define BIN_CHUNK 4096  // edges per b3 block

typedef __attribute__((ext_vector_type(8))) short short8;
typedef __attribute__((ext_vector_type(4))) float f32x4;

__device__ __forceinline__ float lrelu(float x) {
    return fmaxf(x, NEG * x);   // valid for NEG<1
}
__device__ __forceinline__ short f2bf(float f) {
    __hip_bfloat16 b = __float2bfloat16(f);
    return *(short*)&b;
}

// ---- init: bucket cursors + fused attention weights ----
// Wa[k][i] (i<8: src head i, i>=8: dst head i-8) = sum_c W[k][hd*16+c]*att[hd*16+c]
// Exact algebra: a_src = (x@W)@att_src == x@Wa_src -> logits ride the MFMA.
__global__ void init_kernel(const float* __restrict__ W,
                            const float* __restrict__ att_src,
                            const float* __restrict__ att_dst,
                            float* __restrict__ wa,
                            int* __restrict__ cursor, int nbuck)
{
    int t = threadIdx.x;
    if (t < nbuck) cursor[t] = t * BK_CAP;
    for (int idx = t; idx < IN_CH * 16; idx += 256) {
        int k = idx >> 4, i = idx & 15;
        const float* av = (i < 8) ? att_src : att_dst;
        int hd = (i < 8) ? i : i - 8;
        float s = 0.f;
        #pragma unroll
        for (int c = 0; c < 16; ++c)
            s += W[k * HC + hd * 16 + c] * av[hd * 16 + c];
        wa[idx] = s;
    }
}

// ---- projection via MFMA: h = bf16(x) @ bf16(W), logits fused as tile 8 ----
// 64 rows/block, wave w owns rows w*16..w*16+15. 9 N-tiles x 2 K-steps of
// mfma_f32_16x16x32_bf16. A: lane holds x[row=l&15][ (l>>4)*8+j ]; B: lane
// holds W[k][col=l&15]; D: col=l&15, row=(l>>4)*4+reg (verified layout).
__global__ __launch_bounds__(256) void proj_kernel(
    const float* __restrict__ x, const float* __restrict__ W,
    const float* __restrict__ wa,
    __hip_bfloat16* __restrict__ hb, float* __restrict__ asrc,
    float* __restrict__ adst, int n)
{
    int lane = threadIdx.x & 63;
    int w    = threadIdx.x >> 6;
    int m    = lane & 15;     // A-row / B-col / D-col
    int kg   = lane >> 4;     // k-group

    int rowbase = blockIdx.x * 64 + w * 16;

    // B fragments: 8 W-tiles + 1 fused-att tile, both K-steps (~72 VGPR)
    short8 bf[9][2];
    #pragma unroll
    for (int s = 0; s < 2; ++s) {
        #pragma unroll
        for (int t = 0; t < 8; ++t) {
            #pragma unroll
            for (int j = 0; j < 8; ++j) {
                int k = s * 32 + kg * 8 + j;
                bf[t][s][j] = f2bf(W[k * HC + t * 16 + m]);
            }
        }
        #pragma unroll
        for (int j = 0; j < 8; ++j) {
            int k = s * 32 + kg * 8 + j;
            bf[8][s][j] = f2bf(wa[k * 16 + m]);
        }
    }

    // A fragments: x row (clamped for tail block)
    int rowc = min(rowbase + m, n - 1);
    const float* xp = x + (long long)rowc * IN_CH + kg * 8;
    short8 af[2];
    #pragma unroll
    for (int s = 0; s < 2; ++s) {
        float4 f0 = *(const float4*)(xp + s * 32);
        float4 f1 = *(const float4*)(xp + s * 32 + 4);
        af[s][0] = f2bf(f0.x); af[s][1] = f2bf(f0.y);
        af[s][2] = f2bf(f0.z); af[s][3] = f2bf(f0.w);
        af[s][4] = f2bf(f1.x); af[s][5] = f2bf(f1.y);
        af[s][6] = f2bf(f1.z); af[s][7] = f2bf(f1.w);
    }

    f32x4 acc[9];
    #pragma unroll
    for (int t = 0; t < 9; ++t) acc[t] = (f32x4){0.f, 0.f, 0.f, 0.f};

    #pragma unroll
    for (int s = 0; s < 2; ++s)
        #pragma unroll
        for (int t = 0; t < 9; ++t)
            acc[t] = __builtin_amdgcn_mfma_f32_16x16x32_bf16(
                         af[s], bf[t][s], acc[t], 0, 0, 0);

    #pragma unroll
    for (int r = 0; r < 4; ++r) {
        int orow = rowbase + kg * 4 + r;
        if (orow < n) {
            __hip_bfloat16* hp = hb + (long long)orow * HC + m;
            #pragma unroll
            for (int t = 0; t < 8; ++t)
                hp[t * 16] = __float2bfloat16(acc[t][r]);
            float av = acc[8][r];
            if (m < 8) asrc[orow * HEADS + m] = av;
            else       adst[orow * HEADS + (m - 8)] = av;
        }
    }
}

// ---- bucketed CSR build (fixed-capacity padded buckets) ----
__global__ __launch_bounds__(256) void b3_bin(
    const int* __restrict__ ei, int E, int nbuck,
    int* __restrict__ cursor, unsigned* __restrict__ binned)
{
    __shared__ int cnt[256];
    __shared__ int resv[256];
    int tid = threadIdx.x;
    int chunk0 = blockIdx.x * BIN_CHUNK;
    cnt[tid] = 0;
    __syncthreads();
    for (int i = tid; i < BIN_CHUNK; i += 256) {
        int e = chunk0 + i;
        if (e < E) atomicAdd(&cnt[ei[E + e] >> BK_BITS], 1);
    }
    __syncthreads();
    if (tid < nbuck) resv[tid] = cnt[tid] ? atomicAdd(&cursor[tid], cnt[tid]) : 0;
    __syncthreads();
    for (int i = tid; i < BIN_CHUNK; i += 256) {
        int e = chunk0 + i;
        if (e < E) {
            int s = ei[e], d = ei[E + e];
            int b = d >> BK_BITS;
            int p = atomicAdd(&resv[b], 1);
            binned[p] = (unsigned)s | ((unsigned)(d & (BK_SIZE - 1)) << 20);
        }
    }
}

__global__ __launch_bounds__(256) void b4_build(
    const unsigned* __restrict__ binned, const int* __restrict__ cursor,
    int2* __restrict__ row2, int* __restrict__ csr, int n)
{
    __shared__ int deg[BK_SIZE];
    __shared__ int off[BK_SIZE];
    __shared__ int ts[256];
    int tid = threadIdx.x;
    int b = blockIdx.x;
    int node0 = b << BK_BITS;
    int nn = min(BK_SIZE, n - node0);
    int e0 = b * BK_CAP;
    int e1 = cursor[b];     // final cursor = e0 + bucket count

    for (int i = tid; i < BK_SIZE; i += 256) deg[i] = 0;
    __syncthreads();
    for (int j = e0 + tid; j < e1; j += 256)
        atomicAdd(&deg[binned[j] >> 20], 1);
    __syncthreads();

    int base4 = tid * 4;
    int v0 = deg[base4], v1 = deg[base4 + 1], v2 = deg[base4 + 2], v3 = deg[base4 + 3];
    int ssum = v0 + v1 + v2 + v3;
    ts[tid] = ssum;
    __syncthreads();
    for (int o = 1; o < 256; o <<= 1) {
        int xv = (tid >= o) ? ts[tid - o] : 0;
        __syncthreads();
        ts[tid] += xv;
        __syncthreads();
    }
    int run = ts[tid] - ssum;
    off[base4 + 0] = run;
    if (base4 + 0 < nn) row2[node0 + base4 + 0] = make_int2(e0 + run, e0 + run + v0);
    run += v0;
    off[base4 + 1] = run;
    if (base4 + 1 < nn) row2[node0 + base4 + 1] = make_int2(e0 + run, e0 + run + v1);
    run += v1;
    off[base4 + 2] = run;
    if (base4 + 2 < nn) row2[node0 + base4 + 2] = make_int2(e0 + run, e0 + run + v2);
    run += v2;
    off[base4 + 3] = run;
    if (base4 + 3 < nn) row2[node0 + base4 + 3] = make_int2(e0 + run, e0 + run + v3);
    __syncthreads();

    for (int i = tid; i < BK_SIZE; i += 256) deg[i] = off[i];
    __syncthreads();
    for (int j = e0 + tid; j < e1; j += 256) {
        unsigned pk = binned[j];
        int dl = pk >> 20;
        int s = (int)(pk & 0xFFFFFu);
        int p = atomicAdd(&deg[dl], 1);
        csr[e0 + p] = s;
    }
}

// ---- fused softmax + aggregation: own-head exp, no cross-lane ops ----
__global__ __launch_bounds__(256) void agg_kernel(
    const int* __restrict__ csr, const int2* __restrict__ row2,
    const float* __restrict__ asrc, const float* __restrict__ adst,
    const __hip_bfloat16* __restrict__ hb, const float* __restrict__ bias,
    float* __restrict__ out, int n)
{
    int wave = threadIdx.x >> 6;
    int lane = threadIdx.x & 63;
    int d = blockIdx.x * 4 + wave;
    if (d >= n) return;

    int hO = lane >> 3;         // head owning this lane's output cols

    int2 se = row2[d];
    int start = se.x, end = se.y;

    float adstv = adst[d * HEADS + hO];
    const unsigned* hu = (const unsigned*)hb;

    // self loop
    float w = __expf(lrelu(asrc[d * HEADS + hO] + adstv));
    unsigned u = hu[(long long)d * 64 + lane];
    float denom = w;
    float accx = w * __uint_as_float(u << 16);
    float accy = w * __uint_as_float(u & 0xFFFF0000u);

    int j = start;
    for (; j + 3 < end; j += 4) {
        int s0 = csr[j], s1 = csr[j + 1], s2 = csr[j + 2], s3 = csr[j + 3];
        float w0 = __expf(lrelu(asrc[s0 * HEADS + hO] + adstv));
        float w1 = __expf(lrelu(asrc[s1 * HEADS + hO] + adstv));
        float w2 = __expf(lrelu(asrc[s2 * HEADS + hO] + adstv));
        float w3 = __expf(lrelu(asrc[s3 * HEADS + hO] + adstv));
        unsigned u0 = hu[(long long)s0 * 64 + lane];
        unsigned u1 = hu[(long long)s1 * 64 + lane];
        unsigned u2 = hu[(long long)s2 * 64 + lane];
        unsigned u3 = hu[(long long)s3 * 64 + lane];
        denom += (w0 + w1) + (w2 + w3);
        accx = fmaf(w0, __uint_as_float(u0 << 16), accx);
        accy = fmaf(w0, __uint_as_float(u0 & 0xFFFF0000u), accy);
        accx = fmaf(w1, __uint_as_float(u1 << 16), accx);
        accy = fmaf(w1, __uint_as_float(u1 & 0xFFFF0000u), accy);
        accx = fmaf(w2, __uint_as_float(u2 << 16), accx);
        accy = fmaf(w2, __uint_as_float(u2 & 0xFFFF0000u), accy);
        accx = fmaf(w3, __uint_as_float(u3 << 16), accx);
        accy = fmaf(w3, __uint_as_float(u3 & 0xFFFF0000u), accy);
    }
    for (; j < end; ++j) {
        int s0 = csr[j];
        float w0 = __expf(lrelu(asrc[s0 * HEADS + hO] + adstv));
        unsigned u0 = hu[(long long)s0 * 64 + lane];
        denom += w0;
        accx = fmaf(w0, __uint_as_float(u0 << 16), accx);
        accy = fmaf(w0, __uint_as_float(u0 & 0xFFFF0000u), accy);
    }

    float inv = 1.f / (denom + 1e-16f);
    const float2* b2 = (const float2*)bias;
    float2 bb = b2[lane];
    float2 o;
    o.x = fmaxf(fmaf(accx, inv, bb.x), 0.f);
    o.y = fmaxf(fmaf(accy, inv, bb.y), 0.f);
    ((float2*)out)[(long long)d * 64 + lane] = o;
}

extern "C" void kernel_launch(void* const* d_in, const int* in_sizes, int n_in,
                              void* d_out, int out_size, void* d_ws, size_t ws_size,
                              hipStream_t stream) {
    const float* x       = (const float*)d_in[0];
    const float* W       = (const float*)d_in[1];
    const float* att_src = (const float*)d_in[2];
    const float* att_dst = (const float*)d_in[3];
    const float* bias    = (const float*)d_in[4];
    const int*   ei      = (const int*)d_in[5];

    int n = in_sizes[0] / IN_CH;        // 100000
    int E = in_sizes[5] / 2;            // 1600000
    float* out = (float*)d_out;
    int nbuck = (n + BK_SIZE - 1) >> BK_BITS;   // 98 (<=256 required)

    // workspace layout
    char* ws = (char*)d_ws;
    __hip_bfloat16* hb = (__hip_bfloat16*)ws; ws += (size_t)n * HC * 2;  // 25.6 MB
    float* asrc = (float*)ws;   ws += (size_t)n * HEADS * 4;             // 3.2 MB
    float* adst = (float*)ws;   ws += (size_t)n * HEADS * 4;             // 3.2 MB
    int*   csr  = (int*)ws;     ws += ((size_t)nbuck * BK_CAP + 64) * 4; // 7.2 MB
    unsigned* binned = (unsigned*)ws; ws += (size_t)nbuck * BK_CAP * 4;  // 7.2 MB
    int2*  row2 = (int2*)ws;    ws += (size_t)n * 8;                     // 0.8 MB
    int*   cursor=(int*)ws;     ws += 256 * 4;
    float* wa   = (float*)ws;   ws += IN_CH * 16 * 4;                    // 4 KB

    init_kernel<<<1, 256, 0, stream>>>(W, att_src, att_dst, wa, cursor, nbuck);

    int pblk = (n + 63) / 64;   // 1563
    proj_kernel<<<pblk, 256, 0, stream>>>(x, W, wa, hb, asrc, adst, n);

    int binblk = (E + BIN_CHUNK - 1) / BIN_CHUNK;
    b3_bin<<<binblk, 256, 0, stream>>>(ei, E, nbuck, cursor, binned);
    b4_build<<<nbuck, 256, 0, stream>>>(binned, cursor, row2, csr, n);

    int ablk = (n + 3) / 4;
    agg_kernel<<<ablk, 256, 0, stream>>>(csr, row2, asrc, adst, hb, bias, out, n);
}